// Round 20
// baseline (714.056 us; speedup 1.0000x reference)
//
#include <hip/hip_runtime.h>

// ---------------------------------------------------------------------------
// GIN GraphEncoder on MI355X.
// R20: BARRIER-FREE DIRECT-FRAGMENT GEMM. Operands are L1/L2-resident
// (B-tile 64KB, weights 131KB, A read once) -- LDS staging + per-iteration
// barriers were pure overhead (guide common-mistake #7). Each lane loads its
// MFMA fragment (us8, 16B) straight from global; no LDS, no __syncthreads in
// the K-loop, no swizzle (all buffers flat). Waves independent -> TLP hides
// L2 latency. gemmB applies BN+relu to A-frags in regs (sc/sh LDS table,
// broadcast, one init barrier). Heads: same kernel, 3-product fragments.
// Accumulate order unchanged -> absmax bit-identical.
// R17/18: plain-bf16 main path, bf16 gather. Ledger: BN-fusion -56,
// bf16-gather -120, 64x128 -37, BK64 -21, reg-staged -4 (superseded).
// ---------------------------------------------------------------------------

typedef __attribute__((ext_vector_type(8))) short short8;   // 8 bf16 for MFMA
typedef __attribute__((ext_vector_type(4))) float f32x4;
typedef __attribute__((ext_vector_type(4))) unsigned short us4;
typedef __attribute__((ext_vector_type(8))) unsigned short us8;

__device__ __forceinline__ unsigned short f2bf(float f) {
  unsigned int b = __float_as_uint(f);
  unsigned int r = 0x7FFFu + ((b >> 16) & 1u);   // round-to-nearest-even
  return (unsigned short)((b + r) >> 16);
}
__device__ __forceinline__ float bf2f(unsigned short u) {
  return __uint_as_float(((unsigned int)u) << 16);
}

// ---------------- CSR build + graph bounds (fused) ----------------
__global__ void k_histbounds(const int* __restrict__ ei, int* __restrict__ deg, int E,
                             int eb, const int* __restrict__ batch,
                             int* __restrict__ gs, int* __restrict__ ge, int N) {
  int b = blockIdx.x;
  if (b < eb) {
    int e = b * 256 + threadIdx.x;
    if (e < E) atomicAdd(&deg[ei[E + e]], 1);
  } else {
    int i = (b - eb) * 256 + threadIdx.x;
    if (i < N) {
      int bb = batch[i];
      if (i == 0 || batch[i - 1] != bb) gs[bb] = i;
      if (i == N - 1 || batch[i + 1] != bb) ge[bb] = i + 1;
    }
  }
}

__global__ __launch_bounds__(1024) void k_scan1(const int* __restrict__ deg,
                                                int* __restrict__ partial,
                                                int* __restrict__ bsum, int N) {
  __shared__ int sd[1024];
  int tid = threadIdx.x;
  int i = blockIdx.x * 1024 + tid;
  int v = (i < N) ? deg[i] : 0;
  sd[tid] = v;
  __syncthreads();
  for (int off = 1; off < 1024; off <<= 1) {
    int t = (tid >= off) ? sd[tid - off] : 0;
    __syncthreads();
    sd[tid] += t;
    __syncthreads();
  }
  if (i < N) partial[i] = sd[tid];
  if (tid == 1023) bsum[blockIdx.x] = sd[1023];
}

__global__ void k_scan2(int* __restrict__ bsum, int nb) {
  int l = threadIdx.x;
  int orig = (l < nb) ? bsum[l] : 0;
  int v = orig;
  for (int off = 1; off < 64; off <<= 1) {
    int t = __shfl_up(v, off);
    if (l >= off) v += t;
  }
  if (l < nb) bsum[l] = v - orig;
}

__global__ void k_scan3(const int* __restrict__ deg, const int* __restrict__ partial,
                        const int* __restrict__ bsum, int* __restrict__ rowptr,
                        int* __restrict__ cursor, int N) {
  int i = blockIdx.x * 256 + threadIdx.x;
  if (i >= N) return;
  int incl = partial[i] + bsum[i >> 10];
  rowptr[i + 1] = incl;
  cursor[i] = incl - deg[i];
  if (i == 0) rowptr[0] = 0;
}

__global__ void k_fill(const int* __restrict__ ei, int* __restrict__ cursor,
                       int* __restrict__ adj, int E) {
  int e = blockIdx.x * 256 + threadIdx.x;
  if (e >= E) return;
  int s = ei[e];
  int d = ei[E + e];
  int pos = atomicAdd(&cursor[d], 1);
  adj[pos] = s;
}

// ---- x f32 -> bf16 (one-time; feeds layer-1 gather) ----
__global__ void k_xbf(const float* __restrict__ X, unsigned short* __restrict__ Xb,
                      int total) {
  int t = blockIdx.x * 256 + threadIdx.x;   // one 8-elem group
  if (t * 8 >= total) return;
  const float4 v0 = *(const float4*)(X + t * 8);
  const float4 v1 = *(const float4*)(X + t * 8 + 4);
  us8 o;
  o[0] = f2bf(v0.x); o[1] = f2bf(v0.y); o[2] = f2bf(v0.z); o[3] = f2bf(v0.w);
  o[4] = f2bf(v1.x); o[5] = f2bf(v1.y); o[6] = f2bf(v1.z); o[7] = f2bf(v1.w);
  *(us8*)(Xb + t * 8) = o;
}

// ---- ALL weights: transpose + bf16 (hi) + residual (lo), FLAT Wt[n][k] ----
__global__ void k_prep_all(const float* __restrict__ w1a, const float* __restrict__ w1b,
                           const float* __restrict__ w2a, const float* __restrict__ w2b,
                           const float* __restrict__ w3a, const float* __restrict__ w3b,
                           const float* __restrict__ wh1, const float* __restrict__ wh2,
                           unsigned short* __restrict__ Hi, unsigned short* __restrict__ Lo) {
  int idx = blockIdx.x * 256 + threadIdx.x;   // [0, 884736)
  const float* W; int K, Nout, lo_;
  if (idx < 32768)       { W = w1a; K = 128; Nout = 256; lo_ = 0; }
  else if (idx < 98304)  { W = w1b; K = 256; Nout = 256; lo_ = 32768; }
  else if (idx < 163840) { W = w2a; K = 256; Nout = 256; lo_ = 98304; }
  else if (idx < 229376) { W = w2b; K = 256; Nout = 256; lo_ = 163840; }
  else if (idx < 294912) { W = w3a; K = 256; Nout = 256; lo_ = 229376; }
  else if (idx < 360448) { W = w3b; K = 256; Nout = 256; lo_ = 294912; }
  else if (idx < 491520) { W = wh1; K = 256; Nout = 512; lo_ = 360448; }
  else                   { W = wh2; K = 512; Nout = 768; lo_ = 491520; }
  int li = idx - lo_;
  int n = li % Nout, k = li / Nout;
  float w = W[k * Nout + n];
  unsigned short h = f2bf(w);
  size_t oi = (size_t)lo_ + (size_t)n * K + k;
  Hi[oi] = h;
  Lo[oi] = f2bf(w - bf2f(h));   // only heads read Lo
}

// -------- aggregation: h = Xb[i] + sum Xb[adj[e]] (bf16 gather, f32 acc) ----
// Writes h flat bf16. Block 0 zeroes stats[].
template <int C>
__global__ __launch_bounds__(256) void k_agg(const unsigned short* __restrict__ Xb,
                                             unsigned short* __restrict__ Hb,
                                             const int* __restrict__ rowptr,
                                             const int* __restrict__ adj, int N,
                                             float* __restrict__ statsZ) {
  if (blockIdx.x == 0) {
    statsZ[threadIdx.x] = 0.f;
    statsZ[256 + threadIdx.x] = 0.f;
  }
  int node = blockIdx.x * 4 + (threadIdx.x >> 6);
  if (node >= N) return;
  int lane = threadIdx.x & 63;
  int e0 = rowptr[node], e1 = rowptr[node + 1];
  if constexpr (C == 256) {
    us4 ov = *(const us4*)(Xb + (size_t)node * C + lane * 4);
    float a0 = bf2f(ov[0]), a1 = bf2f(ov[1]), a2 = bf2f(ov[2]), a3 = bf2f(ov[3]);
    int e = e0;
    for (; e + 4 <= e1; e += 4) {
      int s0 = adj[e], s1 = adj[e + 1], s2 = adj[e + 2], s3 = adj[e + 3];
      us4 v0 = *(const us4*)(Xb + (size_t)s0 * C + lane * 4);
      us4 v1 = *(const us4*)(Xb + (size_t)s1 * C + lane * 4);
      us4 v2 = *(const us4*)(Xb + (size_t)s2 * C + lane * 4);
      us4 v3 = *(const us4*)(Xb + (size_t)s3 * C + lane * 4);
      a0 += (bf2f(v0[0]) + bf2f(v1[0])) + (bf2f(v2[0]) + bf2f(v3[0]));
      a1 += (bf2f(v0[1]) + bf2f(v1[1])) + (bf2f(v2[1]) + bf2f(v3[1]));
      a2 += (bf2f(v0[2]) + bf2f(v1[2])) + (bf2f(v2[2]) + bf2f(v3[2]));
      a3 += (bf2f(v0[3]) + bf2f(v1[3])) + (bf2f(v2[3]) + bf2f(v3[3]));
    }
    for (; e < e1; ++e) {
      us4 v = *(const us4*)(Xb + (size_t)adj[e] * C + lane * 4);
      a0 += bf2f(v[0]); a1 += bf2f(v[1]); a2 += bf2f(v[2]); a3 += bf2f(v[3]);
    }
    us4 hv;
    hv[0] = f2bf(a0); hv[1] = f2bf(a1); hv[2] = f2bf(a2); hv[3] = f2bf(a3);
    *(us4*)(Hb + (size_t)node * C + lane * 4) = hv;
  } else {  // C == 128
    ushort2 ov = *(const ushort2*)(Xb + (size_t)node * C + lane * 2);
    float a0 = bf2f(ov.x), a1 = bf2f(ov.y);
    int e = e0;
    for (; e + 4 <= e1; e += 4) {
      int s0 = adj[e], s1 = adj[e + 1], s2 = adj[e + 2], s3 = adj[e + 3];
      ushort2 v0 = *(const ushort2*)(Xb + (size_t)s0 * C + lane * 2);
      ushort2 v1 = *(const ushort2*)(Xb + (size_t)s1 * C + lane * 2);
      ushort2 v2 = *(const ushort2*)(Xb + (size_t)s2 * C + lane * 2);
      ushort2 v3 = *(const ushort2*)(Xb + (size_t)s3 * C + lane * 2);
      a0 += (bf2f(v0.x) + bf2f(v1.x)) + (bf2f(v2.x) + bf2f(v3.x));
      a1 += (bf2f(v0.y) + bf2f(v1.y)) + (bf2f(v2.y) + bf2f(v3.y));
    }
    for (; e < e1; ++e) {
      ushort2 v = *(const ushort2*)(Xb + (size_t)adj[e] * C + lane * 2);
      a0 += bf2f(v.x); a1 += bf2f(v.y);
    }
    ushort2 hv = {f2bf(a0), f2bf(a1)};
    *(ushort2*)(Hb + (size_t)node * C + lane * 2) = hv;
  }
}

// ------- MFMA GEMM: 64x128 tile, DIRECT-FRAGMENT, no LDS / no barriers ------
// Each lane loads its mfma_16x16x32 fragments (us8) straight from global:
//   A[row = m0+wm*32+mi*16+(lane&15)][k = kb+(lane>>4)*8 ..+8]
//   B[col = n0+wn*64+ni*16+(lane&15)][k likewise]   (Wt flat [n][k])
// FULL=false (main): 1-product bf16 x bf16.  ASRC=2: BN+relu applied to the
// A-frag in registers (sc/sh from LDS table, broadcast; one init barrier).
// FULL=true (heads): 3-product split (aHi*wHi + aHi*wLo + aLo*wHi).
// EPI: 0 none, 1 relu, 2 tanh, 3 relu(tanh). OBF16: bf16 out (z / act).
// OSPLIT: flat hi/lo out (head1, relu). STATS: fused BN sum/sumsq.
// XSWZ: XCD-pair swizzle (B shared within an XCD's L2).
template <int EPI, bool STATS, bool OSPLIT, bool XSWZ, int ASRC, bool FULL, bool OBF16>
__global__ __launch_bounds__(256) void k_gemm(
    const unsigned short* __restrict__ AHb, const unsigned short* __restrict__ ALo,
    const unsigned short* __restrict__ Zb,
    int M, int K, int Nld, int mb, int per,
    const unsigned short* __restrict__ WHi, const unsigned short* __restrict__ WLo,
    const float* __restrict__ bias,
    const float* __restrict__ statsIn, const float* __restrict__ gvec,
    const float* __restrict__ bevec,
    float* __restrict__ Out, unsigned short* __restrict__ OutB,
    unsigned short* __restrict__ OHi, unsigned short* __restrict__ OLo,
    float* __restrict__ statsOut) {
  __shared__ float sBNsc[ASRC == 2 ? 256 : 1], sBNsh[ASRC == 2 ? 256 : 1];
  int bx, by;
  if constexpr (XSWZ) {
    int xcd = blockIdx.x & 7, slot = blockIdx.x >> 3;
    bx = xcd * per + (slot >> 1);
    by = slot & 1;
    if (bx >= mb) return;
  } else {
    bx = blockIdx.x;
    by = blockIdx.y;
  }
  const int tid = threadIdx.x;
  const int lane = tid & 63, w = tid >> 6;
  const int wm = w >> 1, wn = w & 1;
  const int m0 = bx * 64, n0 = by * 128;

  if constexpr (ASRC == 2) {
    float mu = statsIn[tid] / (float)M;
    float var = statsIn[256 + tid] / (float)M - mu * mu;
    float sc = gvec[tid] * rsqrtf(var + 1e-5f);
    sBNsc[tid] = sc;
    sBNsh[tid] = bevec[tid] - mu * sc;
    __syncthreads();   // publish BN consts (only barrier in the kernel)
  }

  f32x4 zero = {0.f, 0.f, 0.f, 0.f};
  f32x4 acc[2][4];
#pragma unroll
  for (int i = 0; i < 2; ++i)
#pragma unroll
    for (int j = 0; j < 4; ++j) acc[i][j] = zero;

  const int fr = lane & 15;          // fragment row/col
  const int fk = (lane >> 4) * 8;    // fragment k base

  const unsigned short* asrc = (ASRC == 2) ? Zb : AHb;
  const unsigned short* ap[2];
  const unsigned short* bp[4];
#pragma unroll
  for (int mi = 0; mi < 2; ++mi) {
    int ra = m0 + wm * 32 + mi * 16 + fr;
    if (ra >= M) ra = M - 1;         // clamp (junk rows never stored)
    ap[mi] = asrc + (size_t)ra * K + fk;
  }
#pragma unroll
  for (int ni = 0; ni < 4; ++ni)
    bp[ni] = WHi + (size_t)(n0 + wn * 64 + ni * 16 + fr) * K + fk;

  for (int kb = 0; kb < K; kb += 32) {
    us8 av[2], bv[4];
#pragma unroll
    for (int mi = 0; mi < 2; ++mi) av[mi] = *(const us8*)(ap[mi] + kb);
#pragma unroll
    for (int ni = 0; ni < 4; ++ni) bv[ni] = *(const us8*)(bp[ni] + kb);
    if constexpr (ASRC == 2) {
#pragma unroll
      for (int mi = 0; mi < 2; ++mi) {
#pragma unroll
        for (int jj = 0; jj < 8; ++jj) {
          int kc = kb + fk + jj;
          float o = fmaxf(bf2f(av[mi][jj]) * sBNsc[kc] + sBNsh[kc], 0.f);
          av[mi][jj] = f2bf(o);
        }
      }
    }
    if constexpr (FULL) {
      us8 al[2], bl[4];
#pragma unroll
      for (int mi = 0; mi < 2; ++mi) {
        int ra = m0 + wm * 32 + mi * 16 + fr;
        if (ra >= M) ra = M - 1;
        al[mi] = *(const us8*)(ALo + (size_t)ra * K + fk + kb);
      }
#pragma unroll
      for (int ni = 0; ni < 4; ++ni)
        bl[ni] = *(const us8*)(WLo + (size_t)(n0 + wn * 64 + ni * 16 + fr) * K + fk + kb);
#pragma unroll
      for (int mi = 0; mi < 2; ++mi)
#pragma unroll
        for (int ni = 0; ni < 4; ++ni) {
          acc[mi][ni] = __builtin_amdgcn_mfma_f32_16x16x32_bf16(
              (short8)av[mi], (short8)bv[ni], acc[mi][ni], 0, 0, 0);
          acc[mi][ni] = __builtin_amdgcn_mfma_f32_16x16x32_bf16(
              (short8)av[mi], (short8)bl[ni], acc[mi][ni], 0, 0, 0);
          acc[mi][ni] = __builtin_amdgcn_mfma_f32_16x16x32_bf16(
              (short8)al[mi], (short8)bv[ni], acc[mi][ni], 0, 0, 0);
        }
    } else {
#pragma unroll
      for (int mi = 0; mi < 2; ++mi)
#pragma unroll
        for (int ni = 0; ni < 4; ++ni)
          acc[mi][ni] = __builtin_amdgcn_mfma_f32_16x16x32_bf16(
              (short8)av[mi], (short8)bv[ni], acc[mi][ni], 0, 0, 0);
    }
  }

  // epilogue: C/D layout col = lane&15, row = (lane>>4)*4 + r   [m89-verified]
#pragma unroll
  for (int ni = 0; ni < 4; ++ni) {
    int col = n0 + wn * 64 + ni * 16 + (lane & 15);
    float bc = bias[col];
    float s = 0.f, q = 0.f;
#pragma unroll
    for (int mi = 0; mi < 2; ++mi) {
      int rbase = m0 + wm * 32 + mi * 16 + (lane >> 4) * 4;
#pragma unroll
      for (int r = 0; r < 4; ++r) {
        int row = rbase + r;
        if (row < M) {
          float o = acc[mi][ni][r] + bc;
          if (STATS) { s += o; q += o * o; }
          if (OSPLIT) {
            o = fmaxf(o, 0.f);   // relu (head1)
            unsigned short h = f2bf(o);
            size_t oi = (size_t)row * Nld + col;
            OHi[oi] = h;
            OLo[oi] = f2bf(o - bf2f(h));
          } else {
            if (EPI == 1) o = fmaxf(o, 0.f);
            else if (EPI == 2) o = tanhf(o);
            else if (EPI == 3) o = fmaxf(tanhf(o), 0.f);
            if (OBF16) OutB[(size_t)row * Nld + col] = f2bf(o);
            else       Out[(size_t)row * Nld + col] = o;
          }
        }
      }
    }
    if (STATS) {
      s += __shfl_xor(s, 16); s += __shfl_xor(s, 32);
      q += __shfl_xor(q, 16); q += __shfl_xor(q, 32);
      if ((lane >> 4) == 0) {
        atomicAdd(&statsOut[col], s);
        atomicAdd(&statsOut[256 + col], q);
      }
    }
  }
}

// ---------------- pooling (bf16 input, flat hi/lo output for heads) ---------
__global__ __launch_bounds__(256) void k_pool(const unsigned short* __restrict__ Hb,
                                              const int* __restrict__ gs,
                                              const int* __restrict__ ge,
                                              unsigned short* __restrict__ PHi,
                                              unsigned short* __restrict__ PLo) {
  __shared__ float4 red[4][64];
  int gi = blockIdx.x;
  int s = gs[gi], e = ge[gi];
  int w = threadIdx.x >> 6, lane = threadIdx.x & 63;
  float4 acc = {0.f, 0.f, 0.f, 0.f};
  for (int r = s + w; r < e; r += 4) {
    us4 v = *(const us4*)(Hb + (size_t)r * 256 + lane * 4);
    acc.x += bf2f(v[0]); acc.y += bf2f(v[1]);
    acc.z += bf2f(v[2]); acc.w += bf2f(v[3]);
  }
  red[w][lane] = acc;
  __syncthreads();
  if (w == 0) {
    float4 a = red[0][lane], b = red[1][lane], c = red[2][lane], d = red[3][lane];
    float inv = 1.0f / fmaxf((float)(e - s), 1.0f);
    float vv[4] = {(a.x + b.x + c.x + d.x) * inv, (a.y + b.y + c.y + d.y) * inv,
                   (a.z + b.z + c.z + d.z) * inv, (a.w + b.w + c.w + d.w) * inv};
    us4 hv, lv;
#pragma unroll
    for (int j = 0; j < 4; ++j) {
      unsigned short h = f2bf(vv[j]);
      hv[j] = h;
      lv[j] = f2bf(vv[j] - bf2f(h));
    }
    *(us4*)(PHi + (size_t)gi * 256 + lane * 4) = hv;
    *(us4*)(PLo + (size_t)gi * 256 + lane * 4) = lv;
  }
}

// ---------------------------------------------------------------------------
extern "C" void kernel_launch(void* const* d_in, const int* in_sizes, int n_in,
                              void* d_out, int out_size, void* d_ws, size_t ws_size,
                              hipStream_t stream) {
  const float* x      = (const float*)d_in[0];
  const int* ei       = (const int*)d_in[1];    // int32 from harness
  const int* bat      = (const int*)d_in[2];    // int32 from harness
  const float* w1a = (const float*)d_in[3];  const float* b1a = (const float*)d_in[4];
  const float* g1  = (const float*)d_in[5];  const float* be1 = (const float*)d_in[6];
  const float* w1b = (const float*)d_in[7];  const float* b1b = (const float*)d_in[8];
  const float* w2a = (const float*)d_in[9];  const float* b2a = (const float*)d_in[10];
  const float* g2  = (const float*)d_in[11]; const float* be2 = (const float*)d_in[12];
  const float* w2b = (const float*)d_in[13]; const float* b2b = (const float*)d_in[14];
  const float* w3a = (const float*)d_in[15]; const float* b3a = (const float*)d_in[16];
  const float* g3  = (const float*)d_in[17]; const float* be3 = (const float*)d_in[18];
  const float* w3b = (const float*)d_in[19]; const float* b3b = (const float*)d_in[20];
  const float* wh1 = (const float*)d_in[21]; const float* bh1 = (const float*)d_in[22];
  const float* wh2 = (const float*)d_in[23]; const float* bh2 = (const float*)d_in[24];
  float* out = (float*)d_out;

  const int N = in_sizes[0] / 128;   // 50000
  const int E = in_sizes[1] / 2;     // 800000
  const int G = 512;

  // ---- workspace: 3 flat bf16 buffers (h | z | act) + bf16 x ----
  char* ws = (char*)d_ws;
  size_t off = 0;
  auto alloc = [&](size_t bytes) {
    void* p = ws + off;
    off = (off + bytes + 255) & ~(size_t)255;
    return p;
  };
  unsigned short* hb = (unsigned short*)alloc((size_t)N * 256 * 2);
  unsigned short* zb = (unsigned short*)alloc((size_t)N * 256 * 2);
  unsigned short* ab = (unsigned short*)alloc((size_t)N * 256 * 2);
  unsigned short* xb = (unsigned short*)alloc((size_t)N * 128 * 2);
  int* adj     = (int*)alloc((size_t)E * 4);
  int* rowptr  = (int*)alloc((size_t)(N + 1) * 4);
  int* cursor  = (int*)alloc((size_t)N * 4);
  int* deg     = (int*)alloc((size_t)N * 4);
  int* partial = (int*)alloc((size_t)N * 4);
  int* bsum    = (int*)alloc(64 * 4);
  unsigned short* wHi = (unsigned short*)alloc(884736 * 2);
  unsigned short* wLo = (unsigned short*)alloc(884736 * 2);
  float* stats = (float*)alloc(512 * 4);
  int* gs      = (int*)alloc(G * 4);
  int* ge      = (int*)alloc(G * 4);
  unsigned short* poolHi = (unsigned short*)alloc((size_t)G * 256 * 2);
  unsigned short* poolLo = (unsigned short*)alloc((size_t)G * 256 * 2);
  unsigned short* thidHi = (unsigned short*)alloc((size_t)G * 512 * 2);
  unsigned short* thidLo = (unsigned short*)alloc((size_t)G * 512 * 2);

  // transposed-weight element offsets (match k_prep_all segment table)
  const int o1a = 0, o1b = 32768, o2a = 98304, o2b = 163840, o3a = 229376, o3b = 294912;
  const int oh1 = 360448, oh2 = 491520;   // ends at 884736

  hipMemsetAsync(deg, 0, (size_t)N * 4, stream);
  hipMemsetAsync(gs, 0, (size_t)G * 4, stream);
  hipMemsetAsync(ge, 0, (size_t)G * 4, stream);

  int eb = (E + 255) / 256;
  int nbN = (N + 255) / 256;
  int nb1 = (N + 1023) >> 10;   // 49 (<=64 required by k_scan2)
  k_histbounds<<<eb + nbN, 256, 0, stream>>>(ei, deg, E, eb, bat, gs, ge, N);
  k_scan1<<<nb1, 1024, 0, stream>>>(deg, partial, bsum, N);
  k_scan2<<<1, 64, 0, stream>>>(bsum, nb1);
  k_scan3<<<nbN, 256, 0, stream>>>(deg, partial, bsum, rowptr, cursor, N);
  k_fill<<<eb, 256, 0, stream>>>(ei, cursor, adj, E);

  k_xbf<<<(N * 128 / 8 + 255) / 256, 256, 0, stream>>>(x, xb, N * 128);
  k_prep_all<<<3456, 256, 0, stream>>>(w1a, w1b, w2a, w2b, w3a, w3b, wh1, wh2, wHi, wLo);

  int nb4 = (N + 3) / 4;
  const int mb = (N + 63) / 64;          // 782 M-tiles of 64 rows
  const int per = (mb + 7) / 8;          // 98
  dim3 gg(per * 16);                     // XCD-pair swizzled flat grid (1568)

  // ---- layer 1: xb -> h@hb -> z@zb -> act@ab ----
  k_agg<128><<<nb4, 256, 0, stream>>>(xb, hb, rowptr, adj, N, stats);
  k_gemm<0, true, false, true, 0, false, true><<<gg, 256, 0, stream>>>(
      hb, nullptr, nullptr, N, 128, 256, mb, per, wHi + o1a, wLo + o1a, b1a,
      nullptr, nullptr, nullptr, nullptr, zb, nullptr, nullptr, stats);
  k_gemm<1, false, false, true, 2, false, true><<<gg, 256, 0, stream>>>(
      nullptr, nullptr, zb, N, 256, 256, mb, per, wHi + o1b, wLo + o1b, b1b,
      stats, g1, be1, nullptr, ab, nullptr, nullptr, nullptr);

  // ---- layer 2: act@ab -> h@hb -> z@zb -> act@ab ----
  k_agg<256><<<nb4, 256, 0, stream>>>(ab, hb, rowptr, adj, N, stats);
  k_gemm<0, true, false, true, 0, false, true><<<gg, 256, 0, stream>>>(
      hb, nullptr, nullptr, N, 256, 256, mb, per, wHi + o2a, wLo + o2a, b2a,
      nullptr, nullptr, nullptr, nullptr, zb, nullptr, nullptr, stats);
  k_gemm<3, false, false, true, 2, false, true><<<gg, 256, 0, stream>>>(
      nullptr, nullptr, zb, N, 256, 256, mb, per, wHi + o2b, wLo + o2b, b2b,
      stats, g2, be2, nullptr, ab, nullptr, nullptr, nullptr);

  // ---- layer 3: act@ab -> h@hb -> z@zb -> act@ab ----
  k_agg<256><<<nb4, 256, 0, stream>>>(ab, hb, rowptr, adj, N, stats);
  k_gemm<0, true, false, true, 0, false, true><<<gg, 256, 0, stream>>>(
      hb, nullptr, nullptr, N, 256, 256, mb, per, wHi + o3a, wLo + o3a, b3a,
      nullptr, nullptr, nullptr, nullptr, zb, nullptr, nullptr, stats);
  k_gemm<2, false, false, true, 2, false, true><<<gg, 256, 0, stream>>>(
      nullptr, nullptr, zb, N, 256, 256, mb, per, wHi + o3b, wLo + o3b, b3b,
      stats, g3, be3, nullptr, ab, nullptr, nullptr, nullptr);

  // ---- pool + MFMA heads (heads: FULL 3-product, direct fragments) ----
  k_pool<<<G, 256, 0, stream>>>(ab, gs, ge, poolHi, poolLo);
  dim3 gh1(8, 4);   // M=512/64 tiles, N=512/128 col-halves
  k_gemm<1, false, true, false, 0, true, false><<<gh1, 256, 0, stream>>>(
      poolHi, poolLo, nullptr, G, 256, 512, 0, 0, wHi + oh1, wLo + oh1, bh1,
      nullptr, nullptr, nullptr, nullptr, nullptr, thidHi, thidLo, nullptr);
  dim3 gh2(8, 6);   // M=512/64 tiles, N=768/128 col-halves
  k_gemm<0, false, false, false, 0, true, false><<<gh2, 256, 0, stream>>>(
      thidHi, thidLo, nullptr, G, 512, 768, 0, 0, wHi + oh2, wLo + oh2, bh2,
      nullptr, nullptr, nullptr, out, nullptr, nullptr, nullptr, nullptr);
}

// Round 21
// 575.755 us; speedup vs baseline: 1.2402x; 1.2402x over previous
//
#include <hip/hip_runtime.h>

// ---------------------------------------------------------------------------
// GIN GraphEncoder on MI355X.  (R21 = exact revert to R19, the measured best:
// 577us. R20's barrier-free direct-fragment GEMM regressed to 714us -- LDS
// staging amortizes L2 round-trips across waves; removing it ballooned
// per-wave cache traffic. Lesson ledgered.)
// R19: FULL REG-STAGED GEMM PIPELINE (T14 everywhere). Each iter: ds_write
// regs -> barrier -> issue NEXT tile's global loads into regs -> MFMA ->
// barrier. Heads keep gload16. BK=64, 24KB LDS, sw8 swizzle, plain-bf16
// main path, bf16 gather, XCD-pair swizzle.
// Ledger: BN-fusion -56, 2-product -17, bf16-gather -120, T14(A) -21,
// 64x128 -37, plain-bf16 -15, BK64 -21, reg-staged -4, direct-frag +137(rev).
// ---------------------------------------------------------------------------

typedef __attribute__((ext_vector_type(8))) short short8;   // 8 bf16 for MFMA
typedef __attribute__((ext_vector_type(4))) float f32x4;
typedef __attribute__((ext_vector_type(4))) unsigned short us4;
typedef __attribute__((ext_vector_type(8))) unsigned short us8;

__device__ __forceinline__ unsigned short f2bf(float f) {
  unsigned int b = __float_as_uint(f);
  unsigned int r = 0x7FFFu + ((b >> 16) & 1u);   // round-to-nearest-even
  return (unsigned short)((b + r) >> 16);
}
__device__ __forceinline__ float bf2f(unsigned short u) {
  return __uint_as_float(((unsigned int)u) << 16);
}

// bank-spread row swizzle (8-slot domain; LDS rows are 128B = bank space)
__device__ __forceinline__ int sw8(int row) {
  return (row & 7) ^ ((row >> 3) & 7);
}

// global->LDS 16B async copy (heads only); LDS dest is wave-uniform base
typedef const __attribute__((address_space(1))) unsigned int* gas1;
typedef __attribute__((address_space(3))) unsigned int* las3;
__device__ __forceinline__ void gload16(const void* g, void* l) {
  __builtin_amdgcn_global_load_lds((gas1)g, (las3)l, 16, 0, 0);
}

// swizzled flat index of element (row, k), row length K:
// 16B groups XORed within each 64-elem (8-group) block: g' = g ^ sw8(row)
__device__ __forceinline__ size_t swz8_idx(int row, int k, int K) {
  int g = k >> 3;
  return (size_t)row * K + ((g >> 3) << 6) + ((((g & 7) ^ sw8(row)) << 3)) + (k & 7);
}

// ---------------- CSR build + graph bounds (fused) ----------------
__global__ void k_histbounds(const int* __restrict__ ei, int* __restrict__ deg, int E,
                             int eb, const int* __restrict__ batch,
                             int* __restrict__ gs, int* __restrict__ ge, int N) {
  int b = blockIdx.x;
  if (b < eb) {
    int e = b * 256 + threadIdx.x;
    if (e < E) atomicAdd(&deg[ei[E + e]], 1);
  } else {
    int i = (b - eb) * 256 + threadIdx.x;
    if (i < N) {
      int bb = batch[i];
      if (i == 0 || batch[i - 1] != bb) gs[bb] = i;
      if (i == N - 1 || batch[i + 1] != bb) ge[bb] = i + 1;
    }
  }
}

__global__ __launch_bounds__(1024) void k_scan1(const int* __restrict__ deg,
                                                int* __restrict__ partial,
                                                int* __restrict__ bsum, int N) {
  __shared__ int sd[1024];
  int tid = threadIdx.x;
  int i = blockIdx.x * 1024 + tid;
  int v = (i < N) ? deg[i] : 0;
  sd[tid] = v;
  __syncthreads();
  for (int off = 1; off < 1024; off <<= 1) {
    int t = (tid >= off) ? sd[tid - off] : 0;
    __syncthreads();
    sd[tid] += t;
    __syncthreads();
  }
  if (i < N) partial[i] = sd[tid];
  if (tid == 1023) bsum[blockIdx.x] = sd[1023];
}

__global__ void k_scan2(int* __restrict__ bsum, int nb) {
  int l = threadIdx.x;
  int orig = (l < nb) ? bsum[l] : 0;
  int v = orig;
  for (int off = 1; off < 64; off <<= 1) {
    int t = __shfl_up(v, off);
    if (l >= off) v += t;
  }
  if (l < nb) bsum[l] = v - orig;
}

__global__ void k_scan3(const int* __restrict__ deg, const int* __restrict__ partial,
                        const int* __restrict__ bsum, int* __restrict__ rowptr,
                        int* __restrict__ cursor, int N) {
  int i = blockIdx.x * 256 + threadIdx.x;
  if (i >= N) return;
  int incl = partial[i] + bsum[i >> 10];
  rowptr[i + 1] = incl;
  cursor[i] = incl - deg[i];
  if (i == 0) rowptr[0] = 0;
}

__global__ void k_fill(const int* __restrict__ ei, int* __restrict__ cursor,
                       int* __restrict__ adj, int E) {
  int e = blockIdx.x * 256 + threadIdx.x;
  if (e >= E) return;
  int s = ei[e];
  int d = ei[E + e];
  int pos = atomicAdd(&cursor[d], 1);
  adj[pos] = s;
}

// ---- x f32 -> bf16 (one-time; feeds layer-1 gather) ----
__global__ void k_xbf(const float* __restrict__ X, unsigned short* __restrict__ Xb,
                      int total) {
  int t = blockIdx.x * 256 + threadIdx.x;   // one 8-elem group
  if (t * 8 >= total) return;
  const float4 v0 = *(const float4*)(X + t * 8);
  const float4 v1 = *(const float4*)(X + t * 8 + 4);
  us8 o;
  o[0] = f2bf(v0.x); o[1] = f2bf(v0.y); o[2] = f2bf(v0.z); o[3] = f2bf(v0.w);
  o[4] = f2bf(v1.x); o[5] = f2bf(v1.y); o[6] = f2bf(v1.z); o[7] = f2bf(v1.w);
  *(us8*)(Xb + t * 8) = o;
}

// ---- ALL weights: transpose + split + swizzle in ONE kernel ----
__global__ void k_prep_all(const float* __restrict__ w1a, const float* __restrict__ w1b,
                           const float* __restrict__ w2a, const float* __restrict__ w2b,
                           const float* __restrict__ w3a, const float* __restrict__ w3b,
                           const float* __restrict__ wh1, const float* __restrict__ wh2,
                           unsigned short* __restrict__ Hi, unsigned short* __restrict__ Lo) {
  int idx = blockIdx.x * 256 + threadIdx.x;   // [0, 884736)
  const float* W; int K, Nout, lo_;
  if (idx < 32768)       { W = w1a; K = 128; Nout = 256; lo_ = 0; }
  else if (idx < 98304)  { W = w1b; K = 256; Nout = 256; lo_ = 32768; }
  else if (idx < 163840) { W = w2a; K = 256; Nout = 256; lo_ = 98304; }
  else if (idx < 229376) { W = w2b; K = 256; Nout = 256; lo_ = 163840; }
  else if (idx < 294912) { W = w3a; K = 256; Nout = 256; lo_ = 229376; }
  else if (idx < 360448) { W = w3b; K = 256; Nout = 256; lo_ = 294912; }
  else if (idx < 491520) { W = wh1; K = 256; Nout = 512; lo_ = 360448; }
  else                   { W = wh2; K = 512; Nout = 768; lo_ = 491520; }
  int li = idx - lo_;
  int n = li % Nout, k = li / Nout;
  float w = W[k * Nout + n];
  unsigned short h = f2bf(w);
  size_t oi = (size_t)lo_ + swz8_idx(n, k, K);
  Hi[oi] = h;
  Lo[oi] = f2bf(w - bf2f(h));   // only heads read Lo
}

// -------- aggregation: h = Xb[i] + sum Xb[adj[e]] (bf16 gather, f32 acc) ----
// Writes h as single bf16, sw8-swizzled. Block 0 zeroes stats[].
template <int C>
__global__ __launch_bounds__(256) void k_agg(const unsigned short* __restrict__ Xb,
                                             unsigned short* __restrict__ Hb,
                                             const int* __restrict__ rowptr,
                                             const int* __restrict__ adj, int N,
                                             float* __restrict__ statsZ) {
  if (blockIdx.x == 0) {
    statsZ[threadIdx.x] = 0.f;
    statsZ[256 + threadIdx.x] = 0.f;
  }
  int node = blockIdx.x * 4 + (threadIdx.x >> 6);
  if (node >= N) return;
  int lane = threadIdx.x & 63;
  int e0 = rowptr[node], e1 = rowptr[node + 1];
  if constexpr (C == 256) {
    us4 ov = *(const us4*)(Xb + (size_t)node * C + lane * 4);
    float a0 = bf2f(ov[0]), a1 = bf2f(ov[1]), a2 = bf2f(ov[2]), a3 = bf2f(ov[3]);
    int e = e0;
    for (; e + 4 <= e1; e += 4) {
      int s0 = adj[e], s1 = adj[e + 1], s2 = adj[e + 2], s3 = adj[e + 3];
      us4 v0 = *(const us4*)(Xb + (size_t)s0 * C + lane * 4);
      us4 v1 = *(const us4*)(Xb + (size_t)s1 * C + lane * 4);
      us4 v2 = *(const us4*)(Xb + (size_t)s2 * C + lane * 4);
      us4 v3 = *(const us4*)(Xb + (size_t)s3 * C + lane * 4);
      a0 += (bf2f(v0[0]) + bf2f(v1[0])) + (bf2f(v2[0]) + bf2f(v3[0]));
      a1 += (bf2f(v0[1]) + bf2f(v1[1])) + (bf2f(v2[1]) + bf2f(v3[1]));
      a2 += (bf2f(v0[2]) + bf2f(v1[2])) + (bf2f(v2[2]) + bf2f(v3[2]));
      a3 += (bf2f(v0[3]) + bf2f(v1[3])) + (bf2f(v2[3]) + bf2f(v3[3]));
    }
    for (; e < e1; ++e) {
      us4 v = *(const us4*)(Xb + (size_t)adj[e] * C + lane * 4);
      a0 += bf2f(v[0]); a1 += bf2f(v[1]); a2 += bf2f(v[2]); a3 += bf2f(v[3]);
    }
    us4 hv;
    hv[0] = f2bf(a0); hv[1] = f2bf(a1); hv[2] = f2bf(a2); hv[3] = f2bf(a3);
    size_t oi = (size_t)node * 256 + ((lane >> 4) << 6) +
                ((((lane >> 1) & 7) ^ sw8(node)) << 3) + ((lane & 1) << 2);
    *(us4*)(Hb + oi) = hv;
  } else {  // C == 128
    ushort2 ov = *(const ushort2*)(Xb + (size_t)node * C + lane * 2);
    float a0 = bf2f(ov.x), a1 = bf2f(ov.y);
    int e = e0;
    for (; e + 4 <= e1; e += 4) {
      int s0 = adj[e], s1 = adj[e + 1], s2 = adj[e + 2], s3 = adj[e + 3];
      ushort2 v0 = *(const ushort2*)(Xb + (size_t)s0 * C + lane * 2);
      ushort2 v1 = *(const ushort2*)(Xb + (size_t)s1 * C + lane * 2);
      ushort2 v2 = *(const ushort2*)(Xb + (size_t)s2 * C + lane * 2);
      ushort2 v3 = *(const ushort2*)(Xb + (size_t)s3 * C + lane * 2);
      a0 += (bf2f(v0.x) + bf2f(v1.x)) + (bf2f(v2.x) + bf2f(v3.x));
      a1 += (bf2f(v0.y) + bf2f(v1.y)) + (bf2f(v2.y) + bf2f(v3.y));
    }
    for (; e < e1; ++e) {
      ushort2 v = *(const ushort2*)(Xb + (size_t)adj[e] * C + lane * 2);
      a0 += bf2f(v.x); a1 += bf2f(v.y);
    }
    ushort2 hv = {f2bf(a0), f2bf(a1)};
    size_t oi = (size_t)node * 128 + ((lane >> 5) << 6) +
                ((((lane >> 2) & 7) ^ sw8(node)) << 3) + ((lane & 3) << 1);
    *(ushort2*)(Hb + oi) = hv;
  }
}

// ------------ MFMA GEMM: 64x128 tile, BK=64, reg-staged pipeline ------------
// FULL=false (main): 1-product bf16 x bf16, LDS 24KB, REG-STAGED:
//   prologue loads tile0 regs; iter = {ds_write regs, bar, issue next-tile
//   loads, MFMA, bar}. ASRC: 0 = swizzled Hb/act (linear copy to LDS);
//   2 = plain bf16 z + BN+relu applied in WRITE phase (swizzled ds_write).
// FULL=true (heads): 3-product split via gload16 (unchanged).
// EPI: 0 none, 1 relu, 2 tanh, 3 relu(tanh). OBF16: bf16 out (z / act).
// OSPLIT: split+swizzled out (head1, relu). STATS: fused BN sum/sumsq.
// XSWZ: XCD-pair swizzle.
template <int EPI, bool STATS, bool OSPLIT, bool XSWZ, int ASRC, bool FULL, bool OBF16>
__global__ __launch_bounds__(256) void k_gemm(
    const unsigned short* __restrict__ AHb, const unsigned short* __restrict__ ALo,
    const unsigned short* __restrict__ Zb,
    int M, int K, int Nld, int mb, int per,
    const unsigned short* __restrict__ WHi, const unsigned short* __restrict__ WLo,
    const float* __restrict__ bias,
    const float* __restrict__ statsIn, const float* __restrict__ gvec,
    const float* __restrict__ bevec,
    float* __restrict__ Out, unsigned short* __restrict__ OutB,
    unsigned short* __restrict__ OHi, unsigned short* __restrict__ OLo,
    float* __restrict__ statsOut) {
  __shared__ unsigned short aHi[4096], bHi[8192];             // 8K + 16K bytes
  __shared__ unsigned short aLo[FULL ? 4096 : 64], bLo[FULL ? 8192 : 64];
  __shared__ float sBNsc[ASRC == 2 ? 256 : 1], sBNsh[ASRC == 2 ? 256 : 1];
  int bx, by;
  if constexpr (XSWZ) {
    int xcd = blockIdx.x & 7, slot = blockIdx.x >> 3;
    bx = xcd * per + (slot >> 1);
    by = slot & 1;
    if (bx >= mb) return;
  } else {
    bx = blockIdx.x;
    by = blockIdx.y;
  }
  const int tid = threadIdx.x;
  const int lane = tid & 63, w = tid >> 6;
  const int wm = w >> 1, wn = w & 1;
  const int m0 = bx * 64, n0 = by * 128;

  if constexpr (ASRC == 2) {
    float mu = statsIn[tid] / (float)M;
    float var = statsIn[256 + tid] / (float)M - mu * mu;
    float sc = gvec[tid] * rsqrtf(var + 1e-5f);
    sBNsc[tid] = sc;
    sBNsh[tid] = bevec[tid] - mu * sc;
    __syncthreads();   // publish BN consts before first WRITE phase
  }

  f32x4 zero = {0.f, 0.f, 0.f, 0.f};
  f32x4 acc[2][4];
#pragma unroll
  for (int i = 0; i < 2; ++i)
#pragma unroll
    for (int j = 0; j < 4; ++j) acc[i][j] = zero;

  const int l8 = lane >> 3;     // row sub-index in gload staging (heads)
  const int s8 = lane & 7;

  // ---- reg-staging state (main path) ----
  us8 arg[2], brg[4];
  const unsigned short* aptr[2];
  const unsigned short* bptr[4];
  if constexpr (!FULL) {
    const unsigned short* asrc = (ASRC == 2) ? Zb : AHb;
#pragma unroll
    for (int p = 0; p < 2; ++p) {
      int row = (p << 5) + (tid >> 3);
      int ra = m0 + row; if (ra >= M) ra = M - 1;    // clamp (junk never stored)
      aptr[p] = asrc + (size_t)ra * K + (tid & 7) * 8;
      arg[p] = *(const us8*)(aptr[p]);
    }
#pragma unroll
    for (int q = 0; q < 4; ++q) {
      int row = (q << 5) + (tid >> 3);
      bptr[q] = WHi + (size_t)(n0 + row) * K + (tid & 7) * 8;
      brg[q] = *(const us8*)(bptr[q]);
    }
  }

  for (int kb = 0; kb < K; kb += 64) {
    if constexpr (!FULL) {
      // ---- WRITE phase: regs -> LDS ----
      if constexpr (ASRC == 2) {
#pragma unroll
        for (int p = 0; p < 2; ++p) {
          int row = (p << 5) + (tid >> 3), gq = tid & 7;
          us8 hv;
#pragma unroll
          for (int jj = 0; jj < 8; ++jj) {
            int kc = kb + gq * 8 + jj;
            float o = fmaxf(bf2f(arg[p][jj]) * sBNsc[kc] + sBNsh[kc], 0.f);
            hv[jj] = f2bf(o);
          }
          int bo = row * 128 + ((gq ^ sw8(row)) << 4);   // apply swizzle (z is flat)
          *(us8*)((char*)aHi + bo) = hv;
        }
      } else {
#pragma unroll
        for (int p = 0; p < 2; ++p) {
          int row = (p << 5) + (tid >> 3);
          int bo = row * 128 + ((tid & 7) << 4);          // linear (src pre-swizzled)
          *(us8*)((char*)aHi + bo) = arg[p];
        }
      }
#pragma unroll
      for (int q = 0; q < 4; ++q) {
        int row = (q << 5) + (tid >> 3);
        int bo = row * 128 + ((tid & 7) << 4);            // linear (src pre-swizzled)
        *(us8*)((char*)bHi + bo) = brg[q];
      }
      __syncthreads();
      // ---- T14: issue next tile's loads; they complete under MFMA ----
      if (kb + 64 < K) {
#pragma unroll
        for (int p = 0; p < 2; ++p) arg[p] = *(const us8*)(aptr[p] + kb + 64);
#pragma unroll
        for (int q = 0; q < 4; ++q) brg[q] = *(const us8*)(bptr[q] + kb + 64);
      }
    } else {
      // ---- heads: gload16 staging (3-product split) ----
      __syncthreads();
#pragma unroll
      for (int q = 0; q < 2; ++q) {
        int row = (w << 4) + (q << 3) + l8;
        int ra = m0 + row; if (ra >= M) ra = M - 1;
        size_t ga = (size_t)ra * K + kb + s8 * 8;
        unsigned boA = (w << 11) + (q << 10);
        gload16(AHb + ga, (char*)aHi + boA);
        gload16(ALo + ga, (char*)aLo + boA);
      }
#pragma unroll
      for (int q = 0; q < 4; ++q) {
        int row = (w << 5) + (q << 3) + l8;
        size_t gb = (size_t)(n0 + row) * K + kb + s8 * 8;
        unsigned bo2 = (w << 12) + (q << 10);
        gload16(WHi + gb, (char*)bHi + bo2);
        gload16(WLo + gb, (char*)bLo + bo2);
      }
      __syncthreads();
    }

    // ---- COMPUTE phase ----
    const int j = lane >> 4;
#pragma unroll
    for (int kk = 0; kk < 2; ++kk) {
      int g = (kk << 2) + j;        // 16B group within 64-elem row
      short8 bh[4], bl[4];
#pragma unroll
      for (int ni = 0; ni < 4; ++ni) {
        int r = wn * 64 + ni * 16 + (lane & 15);
        int bo = r * 128 + ((g ^ sw8(r)) << 4);
        bh[ni] = *(const short8*)((const char*)bHi + bo);
        if constexpr (FULL) bl[ni] = *(const short8*)((const char*)bLo + bo);
      }
#pragma unroll
      for (int mi = 0; mi < 2; ++mi) {
        int r = wm * 32 + mi * 16 + (lane & 15);
        int bo = r * 128 + ((g ^ sw8(r)) << 4);
        short8 ah = *(const short8*)((const char*)aHi + bo);
#pragma unroll
        for (int ni = 0; ni < 4; ++ni) {
          acc[mi][ni] = __builtin_amdgcn_mfma_f32_16x16x32_bf16(ah, bh[ni], acc[mi][ni], 0, 0, 0);
          if constexpr (FULL) {
            short8 al = *(const short8*)((const char*)aLo + bo);
            acc[mi][ni] = __builtin_amdgcn_mfma_f32_16x16x32_bf16(ah, bl[ni], acc[mi][ni], 0, 0, 0);
            acc[mi][ni] = __builtin_amdgcn_mfma_f32_16x16x32_bf16(al, bh[ni], acc[mi][ni], 0, 0, 0);
          }
        }
      }
    }
    if constexpr (!FULL) __syncthreads();   // release LDS for next WRITE
  }

  // epilogue: C/D layout col = lane&15, row = (lane>>4)*4 + r   [m89-verified]
#pragma unroll
  for (int ni = 0; ni < 4; ++ni) {
    int col = n0 + wn * 64 + ni * 16 + (lane & 15);
    float bc = bias[col];
    float s = 0.f, q = 0.f;
#pragma unroll
    for (int mi = 0; mi < 2; ++mi) {
      int rbase = m0 + wm * 32 + mi * 16 + (lane >> 4) * 4;
#pragma unroll
      for (int r = 0; r < 4; ++r) {
        int row = rbase + r;
        if (row < M) {
          float o = acc[mi][ni][r] + bc;
          if (STATS) { s += o; q += o * o; }
          if (OSPLIT) {
            o = fmaxf(o, 0.f);   // relu (head1)
            unsigned short h = f2bf(o);
            size_t oi = swz8_idx(row, col, Nld);
            OHi[oi] = h;
            OLo[oi] = f2bf(o - bf2f(h));
          } else {
            if (EPI == 1) o = fmaxf(o, 0.f);
            else if (EPI == 2) o = tanhf(o);
            else if (EPI == 3) o = fmaxf(tanhf(o), 0.f);
            if (OBF16) OutB[(size_t)row * Nld + col] = f2bf(o);
            else       Out[(size_t)row * Nld + col] = o;
          }
        }
      }
    }
    if (STATS) {
      s += __shfl_xor(s, 16); s += __shfl_xor(s, 32);
      q += __shfl_xor(q, 16); q += __shfl_xor(q, 32);
      if ((lane >> 4) == 0) {
        atomicAdd(&statsOut[col], s);
        atomicAdd(&statsOut[256 + col], q);
      }
    }
  }
}

// ---------------- pooling (bf16 input, split output for heads) ----------------
__global__ __launch_bounds__(256) void k_pool(const unsigned short* __restrict__ Hb,
                                              const int* __restrict__ gs,
                                              const int* __restrict__ ge,
                                              unsigned short* __restrict__ PHi,
                                              unsigned short* __restrict__ PLo) {
  __shared__ float4 red[4][64];
  int gi = blockIdx.x;
  int s = gs[gi], e = ge[gi];
  int w = threadIdx.x >> 6, lane = threadIdx.x & 63;
  float4 acc = {0.f, 0.f, 0.f, 0.f};
  for (int r = s + w; r < e; r += 4) {
    us4 v = *(const us4*)(Hb + (size_t)r * 256 + lane * 4);
    acc.x += bf2f(v[0]); acc.y += bf2f(v[1]);
    acc.z += bf2f(v[2]); acc.w += bf2f(v[3]);
  }
  red[w][lane] = acc;
  __syncthreads();
  if (w == 0) {
    float4 a = red[0][lane], b = red[1][lane], c = red[2][lane], d = red[3][lane];
    float inv = 1.0f / fmaxf((float)(e - s), 1.0f);
    float vv[4] = {(a.x + b.x + c.x + d.x) * inv, (a.y + b.y + c.y + d.y) * inv,
                   (a.z + b.z + c.z + d.z) * inv, (a.w + b.w + c.w + d.w) * inv};
    us4 hv, lv;
#pragma unroll
    for (int j = 0; j < 4; ++j) {
      unsigned short h = f2bf(vv[j]);
      hv[j] = h;
      lv[j] = f2bf(vv[j] - bf2f(h));
    }
    size_t oi = (size_t)gi * 256 + ((lane >> 4) << 6) +
                ((((lane >> 1) & 7) ^ sw8(gi)) << 3) + ((lane & 1) << 2);
    *(us4*)(PHi + oi) = hv;
    *(us4*)(PLo + oi) = lv;
  }
}

// ---------------------------------------------------------------------------
extern "C" void kernel_launch(void* const* d_in, const int* in_sizes, int n_in,
                              void* d_out, int out_size, void* d_ws, size_t ws_size,
                              hipStream_t stream) {
  const float* x      = (const float*)d_in[0];
  const int* ei       = (const int*)d_in[1];    // int32 from harness
  const int* bat      = (const int*)d_in[2];    // int32 from harness
  const float* w1a = (const float*)d_in[3];  const float* b1a = (const float*)d_in[4];
  const float* g1  = (const float*)d_in[5];  const float* be1 = (const float*)d_in[6];
  const float* w1b = (const float*)d_in[7];  const float* b1b = (const float*)d_in[8];
  const float* w2a = (const float*)d_in[9];  const float* b2a = (const float*)d_in[10];
  const float* g2  = (const float*)d_in[11]; const float* be2 = (const float*)d_in[12];
  const float* w2b = (const float*)d_in[13]; const float* b2b = (const float*)d_in[14];
  const float* w3a = (const float*)d_in[15]; const float* b3a = (const float*)d_in[16];
  const float* g3  = (const float*)d_in[17]; const float* be3 = (const float*)d_in[18];
  const float* w3b = (const float*)d_in[19]; const float* b3b = (const float*)d_in[20];
  const float* wh1 = (const float*)d_in[21]; const float* bh1 = (const float*)d_in[22];
  const float* wh2 = (const float*)d_in[23]; const float* bh2 = (const float*)d_in[24];
  float* out = (float*)d_out;

  const int N = in_sizes[0] / 128;   // 50000
  const int E = in_sizes[1] / 2;     // 800000
  const int G = 512;

  // ---- workspace: 3 bf16 buffers (h swz | z | act) + bf16 x ----
  char* ws = (char*)d_ws;
  size_t off = 0;
  auto alloc = [&](size_t bytes) {
    void* p = ws + off;
    off = (off + bytes + 255) & ~(size_t)255;
    return p;
  };
  unsigned short* hb = (unsigned short*)alloc((size_t)N * 256 * 2);
  unsigned short* zb = (unsigned short*)alloc((size_t)N * 256 * 2);
  unsigned short* ab = (unsigned short*)alloc((size_t)N * 256 * 2);
  unsigned short* xb = (unsigned short*)alloc((size_t)N * 128 * 2);
  int* adj     = (int*)alloc((size_t)E * 4);
  int* rowptr  = (int*)alloc((size_t)(N + 1) * 4);
  int* cursor  = (int*)alloc((size_t)N * 4);
  int* deg     = (int*)alloc((size_t)N * 4);
  int* partial = (int*)alloc((size_t)N * 4);
  int* bsum    = (int*)alloc(64 * 4);
  unsigned short* wHi = (unsigned short*)alloc(884736 * 2);
  unsigned short* wLo = (unsigned short*)alloc(884736 * 2);
  float* stats = (float*)alloc(512 * 4);
  int* gs      = (int*)alloc(G * 4);
  int* ge      = (int*)alloc(G * 4);
  unsigned short* poolHi = (unsigned short*)alloc((size_t)G * 256 * 2);
  unsigned short* poolLo = (unsigned short*)alloc((size_t)G * 256 * 2);
  unsigned short* thidHi = (unsigned short*)alloc((size_t)G * 512 * 2);
  unsigned short* thidLo = (unsigned short*)alloc((size_t)G * 512 * 2);

  // transposed-weight element offsets (match k_prep_all segment table)
  const int o1a = 0, o1b = 32768, o2a = 98304, o2b = 163840, o3a = 229376, o3b = 294912;
  const int oh1 = 360448, oh2 = 491520;   // ends at 884736

  hipMemsetAsync(deg, 0, (size_t)N * 4, stream);
  hipMemsetAsync(gs, 0, (size_t)G * 4, stream);
  hipMemsetAsync(ge, 0, (size_t)G * 4, stream);

  int eb = (E + 255) / 256;
  int nbN = (N + 255) / 256;
  int nb1 = (N + 1023) >> 10;   // 49 (<=64 required by k_scan2)
  k_histbounds<<<eb + nbN, 256, 0, stream>>>(ei, deg, E, eb, bat, gs, ge, N);
  k_scan1<<<nb1, 1024, 0, stream>>>(deg, partial, bsum, N);
  k_scan2<<<1, 64, 0, stream>>>(bsum, nb1);
  k_scan3<<<nbN, 256, 0, stream>>>(deg, partial, bsum, rowptr, cursor, N);
  k_fill<<<eb, 256, 0, stream>>>(ei, cursor, adj, E);

  k_xbf<<<(N * 128 / 8 + 255) / 256, 256, 0, stream>>>(x, xb, N * 128);
  k_prep_all<<<3456, 256, 0, stream>>>(w1a, w1b, w2a, w2b, w3a, w3b, wh1, wh2, wHi, wLo);

  int nb4 = (N + 3) / 4;
  const int mb = (N + 63) / 64;          // 782 M-tiles of 64 rows
  const int per = (mb + 7) / 8;          // 98
  dim3 gg(per * 16);                     // XCD-pair swizzled flat grid (1568)

  // ---- layer 1: xb -> h@hb -> z@zb -> act@ab ----
  k_agg<128><<<nb4, 256, 0, stream>>>(xb, hb, rowptr, adj, N, stats);
  k_gemm<0, true, false, true, 0, false, true><<<gg, 256, 0, stream>>>(
      hb, nullptr, nullptr, N, 128, 256, mb, per, wHi + o1a, wLo + o1a, b1a,
      nullptr, nullptr, nullptr, nullptr, zb, nullptr, nullptr, stats);
  k_gemm<1, false, false, true, 2, false, true><<<gg, 256, 0, stream>>>(
      nullptr, nullptr, zb, N, 256, 256, mb, per, wHi + o1b, wLo + o1b, b1b,
      stats, g1, be1, nullptr, ab, nullptr, nullptr, nullptr);

  // ---- layer 2: act@ab -> h@hb -> z@zb -> act@ab ----
  k_agg<256><<<nb4, 256, 0, stream>>>(ab, hb, rowptr, adj, N, stats);
  k_gemm<0, true, false, true, 0, false, true><<<gg, 256, 0, stream>>>(
      hb, nullptr, nullptr, N, 256, 256, mb, per, wHi + o2a, wLo + o2a, b2a,
      nullptr, nullptr, nullptr, nullptr, zb, nullptr, nullptr, stats);
  k_gemm<3, false, false, true, 2, false, true><<<gg, 256, 0, stream>>>(
      nullptr, nullptr, zb, N, 256, 256, mb, per, wHi + o2b, wLo + o2b, b2b,
      stats, g2, be2, nullptr, ab, nullptr, nullptr, nullptr);

  // ---- layer 3: act@ab -> h@hb -> z@zb -> act@ab ----
  k_agg<256><<<nb4, 256, 0, stream>>>(ab, hb, rowptr, adj, N, stats);
  k_gemm<0, true, false, true, 0, false, true><<<gg, 256, 0, stream>>>(
      hb, nullptr, nullptr, N, 256, 256, mb, per, wHi + o3a, wLo + o3a, b3a,
      nullptr, nullptr, nullptr, nullptr, zb, nullptr, nullptr, stats);
  k_gemm<2, false, false, true, 2, false, true><<<gg, 256, 0, stream>>>(
      nullptr, nullptr, zb, N, 256, 256, mb, per, wHi + o3b, wLo + o3b, b3b,
      stats, g3, be3, nullptr, ab, nullptr, nullptr, nullptr);

  // ---- pool + MFMA heads (heads keep FULL 3-product split) ----
  k_pool<<<G, 256, 0, stream>>>(ab, gs, ge, poolHi, poolLo);
  dim3 gh1(8, 4);   // M=512/64 tiles, N=512/128 col-halves
  k_gemm<1, false, true, false, 0, true, false><<<gh1, 256, 0, stream>>>(
      poolHi, poolLo, nullptr, G, 256, 512, 0, 0, wHi + oh1, wLo + oh1, bh1,
      nullptr, nullptr, nullptr, nullptr, nullptr, thidHi, thidLo, nullptr);
  dim3 gh2(8, 6);   // M=512/64 tiles, N=768/128 col-halves
  k_gemm<0, false, false, false, 0, true, false><<<gh2, 256, 0, stream>>>(
      thidHi, thidLo, nullptr, G, 512, 768, 0, 0, wHi + oh2, wLo + oh2, bh2,
      nullptr, nullptr, nullptr, out, nullptr, nullptr, nullptr, nullptr);
}